// Round 9
// baseline (465.581 us; speedup 1.0000x reference)
//
#include <hip/hip_runtime.h>
#include <hip/hip_bf16.h>

// GaussianCodebook: out[b,s,c] = mean_d((x[b,s,d]-cb[d,c])^2)
//                 = x2[m] + c2[n] - (2/D) * dot(x[m,:], cb[:,n])
// B=8 S=4096 D=512 C=2048  -> GEMM M=32768 N=2048 K=512 (bf16 MFMA) + epilogue.
// R9: 128x128 tile, 256 thr (4 waves, 2Mx2N). Key fix vs R5/R8: combined
//     VGPR+AGPR ~188/wave capped every 512-thr design at 1 block/CU (AGPR
//     acc is invisible in VGPR_Count but counts against the 512 budget).
//     4-wave blocks at ~155-175 combined -> 2-3 blocks/CU co-resident ->
//     real TLP (one block's MFMA covers the other's gate stalls + epilogue
//     stores). A reg-staged 2 tiles ahead (rAs[2][4], macro-literal parity),
//     B gload_lds 2 ahead, 3-deep LDS (48KB). Gates: each step issues
//     exactly 6 vmem ops -> GATE(6) == "pre-this-step loads landed",
//     order-insensitive within the step. Fused prep_x (x2 in-register).

typedef __attribute__((ext_vector_type(8))) short bf16x8;
typedef __attribute__((ext_vector_type(4))) float f32x4;

#define M_ROWS 32768
#define K_DIM  512
#define N_COLS 2048

__device__ __forceinline__ unsigned short f2bf(float f) {
    unsigned int u = __float_as_uint(f);
    return (unsigned short)((u + 0x7fffu + ((u >> 16) & 1u)) >> 16);  // RNE
}

__device__ __forceinline__ void gload_lds16(const void* g, void* l) {
    __builtin_amdgcn_global_load_lds(
        (const __attribute__((address_space(1))) unsigned int*)g,
        (__attribute__((address_space(3))) unsigned int*)l,
        16, 0, 0);
}

// ---- prep_cb: transpose cb [K=512][N=2048] f32 -> cbT [N][K] bf16, scaled by 2/D = 2^-8 ----
__global__ __launch_bounds__(256) void prep_cb_kernel(const float* __restrict__ cb,
                                                      unsigned short* __restrict__ cbT) {
    __shared__ float tile[32][65];
    const int k0 = blockIdx.x * 32;
    const int n0 = blockIdx.y * 64;
    const int tx = threadIdx.x & 63;
    const int ty = threadIdx.x >> 6;
    #pragma unroll
    for (int i = 0; i < 8; ++i) {
        const int k = ty + i * 4;
        tile[k][tx] = cb[(size_t)(k0 + k) * N_COLS + n0 + tx];
    }
    __syncthreads();
    const int kc = threadIdx.x & 31;
    const int nr = threadIdx.x >> 5;
    #pragma unroll
    for (int i = 0; i < 8; ++i) {
        const int n = nr + i * 8;
        cbT[(size_t)(n0 + n) * K_DIM + k0 + kc] = f2bf(tile[kc][n] * 0.00390625f);
    }
}

// ---- c2[n] = mean_k cb[k][n]^2 ----
__global__ __launch_bounds__(256) void c2_kernel(const float* __restrict__ cb,
                                                 float* __restrict__ c2) {
    __shared__ float p[4][64];
    const int t = threadIdx.x;
    const int nl = t & 63;
    const int kc = t >> 6;
    const int n = blockIdx.x * 64 + nl;
    float s = 0.0f;
    for (int k = kc * 128; k < kc * 128 + 128; ++k) {
        float v = cb[(size_t)k * N_COLS + n];
        s += v * v;
    }
    p[kc][nl] = s;
    __syncthreads();
    if (t < 64) {
        c2[blockIdx.x * 64 + t] =
            (p[0][t] + p[1][t] + p[2][t] + p[3][t]) * (1.0f / (float)K_DIM);
    }
}

// ======================= fused 128x128 GEMM, 256 thr =======================
// LDS per buf (shorts): A[128x32] @0 (4096), B[128x32] @4096 (4096) = 16KB; x3 = 48KB.

__device__ __forceinline__ bf16x8 frag_ld(const unsigned short* h, int r, int lhi) {
    const int off = r * 32 + ((lhi ^ ((r >> 1) & 3)) << 3);
    return *reinterpret_cast<const bf16x8*>(&h[off]);
}

#define BAR()  do { asm volatile("" ::: "memory"); \
                    __builtin_amdgcn_s_barrier();  \
                    asm volatile("" ::: "memory"); } while (0)
#define GATE_(n) asm volatile("s_waitcnt vmcnt(" #n ")" ::: "memory")
#define GATE(n) GATE_(n)
#define LGKM0() asm volatile("s_waitcnt lgkmcnt(0)" ::: "memory")

__global__ __launch_bounds__(256, 2) void gemm_kernel(
        const float* __restrict__ X,            // [M][K] f32
        const unsigned short* __restrict__ Bt,  // [N][K] bf16 (scaled by 2^-8)
        const float* __restrict__ c2,
        float* __restrict__ out) {
    __shared__ unsigned short smem[3][8192];    // 48 KiB
    __shared__ float x2s[128];

    const int tid  = threadIdx.x;
    const int wid  = tid >> 6;
    const int lane = tid & 63;
    const int wr64 = (wid >> 1) * 64;       // 2 M-waves
    const int wc64 = (wid & 1) * 64;        // 2 N-waves
    const int l15 = lane & 15;
    const int lhi = lane >> 4;

    // T1: XCD-bijective swizzle (4096 blocks -> 512/XCD); panel-major so the
    // 16 n-blocks of one m-panel co-run on one XCD (A f32 panel 256KB L2-hits).
    const int bid  = blockIdx.x;
    const int lbid = (bid & 7) * 512 + (bid >> 3);
    const int m0 = (lbid >> 4) * 128;
    const int n0 = (lbid & 15) * 128;

    // A reg-staging: 16 floats/thread/step. row = tid>>1, half = tid&1.
    // LDS slot for k-chunk q at row r is q ^ ((r>>1)&3)  (frag_ld inverts).
    const int arow  = tid >> 1;
    const int ahalf = tid & 1;
    const int caw   = (arow >> 1) & 3;
    const int q0s   = (ahalf * 2) ^ caw;
    const float* Ab = X + (size_t)(m0 + arow) * K_DIM + ahalf * 16;

    const unsigned short* Bb = Bt + (size_t)n0 * K_DIM;
    const int rowb0 = tid >> 2;
    const size_t boff0 = (size_t)rowb0 * K_DIM + (((tid & 3) ^ ((rowb0 >> 1) & 3)) * 8);
    const int o16b1 = 256 + tid;
    const int rowb1 = o16b1 >> 2;
    const size_t boff1 = (size_t)rowb1 * K_DIM + (((o16b1 & 3) ^ ((rowb1 >> 1) & 3)) * 8);

    f32x4 acc[4][4] = {};
    float4 rAs[2][4];        // 2 in-flight A tiles; ALL indices macro-literal
    float ss = 0.0f;

#define AISSUE(KT, S) do {                                                     \
    const float4* p_ = reinterpret_cast<const float4*>(Ab + (KT) * 32);        \
    rAs[S][0] = p_[0]; rAs[S][1] = p_[1];                                      \
    rAs[S][2] = p_[2]; rAs[S][3] = p_[3]; } while (0)

#define BISSUE(KT, BUF) do {                                                   \
    gload_lds16(Bb + boff0 + (KT) * 32, &smem[(BUF)][4096 + wid * 512]);       \
    gload_lds16(Bb + boff1 + (KT) * 32, &smem[(BUF)][6144 + wid * 512]); } while (0)

#define AWRITE(BUF, S) do {                                                    \
    union { unsigned short us[16]; bf16x8 v[2]; } u_;                          \
    u_.us[ 0] = f2bf(rAs[S][0].x); u_.us[ 1] = f2bf(rAs[S][0].y);              \
    u_.us[ 2] = f2bf(rAs[S][0].z); u_.us[ 3] = f2bf(rAs[S][0].w);              \
    u_.us[ 4] = f2bf(rAs[S][1].x); u_.us[ 5] = f2bf(rAs[S][1].y);              \
    u_.us[ 6] = f2bf(rAs[S][1].z); u_.us[ 7] = f2bf(rAs[S][1].w);              \
    u_.us[ 8] = f2bf(rAs[S][2].x); u_.us[ 9] = f2bf(rAs[S][2].y);              \
    u_.us[10] = f2bf(rAs[S][2].z); u_.us[11] = f2bf(rAs[S][2].w);              \
    u_.us[12] = f2bf(rAs[S][3].x); u_.us[13] = f2bf(rAs[S][3].y);              \
    u_.us[14] = f2bf(rAs[S][3].z); u_.us[15] = f2bf(rAs[S][3].w);              \
    ss += rAs[S][0].x * rAs[S][0].x + rAs[S][0].y * rAs[S][0].y                \
        + rAs[S][0].z * rAs[S][0].z + rAs[S][0].w * rAs[S][0].w                \
        + rAs[S][1].x * rAs[S][1].x + rAs[S][1].y * rAs[S][1].y                \
        + rAs[S][1].z * rAs[S][1].z + rAs[S][1].w * rAs[S][1].w                \
        + rAs[S][2].x * rAs[S][2].x + rAs[S][2].y * rAs[S][2].y                \
        + rAs[S][2].z * rAs[S][2].z + rAs[S][2].w * rAs[S][2].w                \
        + rAs[S][3].x * rAs[S][3].x + rAs[S][3].y * rAs[S][3].y                \
        + rAs[S][3].z * rAs[S][3].z + rAs[S][3].w * rAs[S][3].w;               \
    *reinterpret_cast<bf16x8*>(&smem[(BUF)][arow * 32 + q0s * 8])       = u_.v[0]; \
    *reinterpret_cast<bf16x8*>(&smem[(BUF)][arow * 32 + (q0s ^ 1) * 8]) = u_.v[1]; } while (0)

// STEP(T): issue A(T+2)+B(T+2) (6 vmem ops), MFMA on buf(T), GATE(6) =
// "all loads older than this step landed" (A(T+1),B(T+1)), write A(T+1).
#define STEP(T)                                                                \
  {                                                                            \
    if ((T) < 14) { AISSUE((T) + 2, (T) & 1); BISSUE((T) + 2, ((T) + 2) % 3); }\
    const unsigned short* cbuf = smem[(T) % 3];                                \
    bf16x8 b[4];                                                               \
    _Pragma("unroll")                                                          \
    for (int nf = 0; nf < 4; ++nf)                                             \
        b[nf] = frag_ld(cbuf + 4096, wc64 + nf * 16 + l15, lhi);               \
    __builtin_amdgcn_s_setprio(1);                                             \
    _Pragma("unroll")                                                          \
    for (int mf = 0; mf < 4; ++mf) {                                           \
        const bf16x8 a = frag_ld(cbuf, wr64 + mf * 16 + l15, lhi);             \
        _Pragma("unroll")                                                      \
        for (int nf = 0; nf < 4; ++nf)                                         \
            acc[mf][nf] = __builtin_amdgcn_mfma_f32_16x16x32_bf16(a, b[nf], acc[mf][nf], 0, 0, 0); \
    }                                                                          \
    __builtin_amdgcn_s_setprio(0);                                             \
    if ((T) < 14) { GATE(6); } else if ((T) == 14) { GATE(0); }                \
    if ((T) < 15) { AWRITE(((T) + 1) % 3, ((T) + 1) & 1); LGKM0(); BAR(); }    \
  }

    // prologue: A(0),B(0),A(1),B(1) in flight (12 ops); GATE(6) -> A(0),B(0)
    // landed, A(1),B(1) stay in flight; write buf0's A; barrier.
    AISSUE(0, 0);
    BISSUE(0, 0);
    AISSUE(1, 1);
    BISSUE(1, 1);
    GATE(6);
    AWRITE(0, 0);
    LGKM0();
    BAR();

    STEP(0)  STEP(1)  STEP(2)  STEP(3)
    STEP(4)  STEP(5)  STEP(6)  STEP(7)
    STEP(8)  STEP(9)  STEP(10) STEP(11)
    STEP(12) STEP(13) STEP(14) STEP(15)

#undef AISSUE
#undef BISSUE
#undef AWRITE
#undef STEP

    // x2[row]: thread covered half-row (256 elems); pair-reduce with tid^1
    ss += __shfl_xor(ss, 1);
    if (ahalf == 0) x2s[arow] = ss * (1.0f / (float)K_DIM);
    __syncthreads();

    // epilogue: C/D layout col = lane&15, row = (lane>>4)*4 + reg
    #pragma unroll
    for (int mf = 0; mf < 4; ++mf) {
        const int lrow = wr64 + mf * 16 + lhi * 4;
        const int mrow = m0 + lrow;
        const float xv0 = x2s[lrow + 0];
        const float xv1 = x2s[lrow + 1];
        const float xv2 = x2s[lrow + 2];
        const float xv3 = x2s[lrow + 3];
        #pragma unroll
        for (int nf = 0; nf < 4; ++nf) {
            const int col = n0 + wc64 + nf * 16 + l15;
            const float cv = c2[col];
            float* o = out + (size_t)mrow * N_COLS + col;
            o[0 * N_COLS] = xv0 + cv - acc[mf][nf][0];
            o[1 * N_COLS] = xv1 + cv - acc[mf][nf][1];
            o[2 * N_COLS] = xv2 + cv - acc[mf][nf][2];
            o[3 * N_COLS] = xv3 + cv - acc[mf][nf][3];
        }
    }
}

extern "C" void kernel_launch(void* const* d_in, const int* in_sizes, int n_in,
                              void* d_out, int out_size, void* d_ws, size_t ws_size,
                              hipStream_t stream) {
    const float* x  = (const float*)d_in[0];   // [8,4096,512]
    const float* cb = (const float*)d_in[1];   // [1,1,512,2048]
    float* out = (float*)d_out;                // [8,4096,2048]

    char* ws = (char*)d_ws;
    unsigned short* cbT = (unsigned short*)ws;                 // 2 MB
    float* c2 = (float*)(ws + (size_t)2097152);                // 8 KB

    prep_cb_kernel<<<dim3(16, 32), 256, 0, stream>>>(cb, cbT);
    c2_kernel<<<N_COLS / 64, 256, 0, stream>>>(cb, c2);
    gemm_kernel<<<dim3((M_ROWS / 128) * (N_COLS / 128)), 256, 0, stream>>>(x, cbT, c2, out);
}

// Round 10
// 126.941 us; speedup vs baseline: 3.6677x; 3.6677x over previous
//
#include <hip/hip_runtime.h>
#include <hip/hip_bf16.h>

// GaussianCodebook: out[b,s,c] = mean_d((x[b,s,d]-cb[d,c])^2)
//                 = x2[m] + c2[n] - (2/D) * dot(x[m,:], cb[:,n])
// B=8 S=4096 D=512 C=2048  -> GEMM M=32768 N=2048 K=512 (bf16 MFMA) + epilogue.
// R10: back to R5's proven structure (prep_x separate; fusion R6-R9 was
//     register-infeasible: 64 AGPR acc is invisible in VGPR_Count but counts
//     against the 512/wave budget -> every fused variant hit 1 block/CU or
//     spilled). Change vs R5: 4-wave 256-thr blocks, 128x128 tile, 64x64 per
//     wave. Combined regs ~150-165 -> 3 waves/SIMD -> 3 blocks/CU -> block
//     TLP overlaps epilogue stores + gate stalls with MFMA (R5 ran 2/SIMD,
//     floors summed). 3-deep LDS pipeline (48KB), GATE(4)/step, T1/T2/T5.

typedef __attribute__((ext_vector_type(8))) short bf16x8;
typedef __attribute__((ext_vector_type(4))) float f32x4;

#define M_ROWS 32768
#define K_DIM  512
#define N_COLS 2048

__device__ __forceinline__ unsigned short f2bf(float f) {
    unsigned int u = __float_as_uint(f);
    return (unsigned short)((u + 0x7fffu + ((u >> 16) & 1u)) >> 16);  // RNE
}

__device__ __forceinline__ void gload_lds16(const void* g, void* l) {
    __builtin_amdgcn_global_load_lds(
        (const __attribute__((address_space(1))) unsigned int*)g,
        (__attribute__((address_space(3))) unsigned int*)l,
        16, 0, 0);
}

// ---- prep_x: cast x f32 -> bf16, and x2[m] = mean_d x^2 ----
__global__ __launch_bounds__(256) void prep_x_kernel(const float* __restrict__ x,
                                                     unsigned short* __restrict__ xb,
                                                     float* __restrict__ x2) {
    const int wid = threadIdx.x >> 6;
    const int lane = threadIdx.x & 63;
    const int row = (blockIdx.x << 2) + wid;
    const float4* p4 = reinterpret_cast<const float4*>(x + (size_t)row * K_DIM);
    float4 v0 = p4[lane];
    float4 v1 = p4[lane + 64];
    float ss = v0.x*v0.x + v0.y*v0.y + v0.z*v0.z + v0.w*v0.w
             + v1.x*v1.x + v1.y*v1.y + v1.z*v1.z + v1.w*v1.w;
    union { unsigned short us[4]; uint2 u2; } pa, pb;
    pa.us[0] = f2bf(v0.x); pa.us[1] = f2bf(v0.y); pa.us[2] = f2bf(v0.z); pa.us[3] = f2bf(v0.w);
    pb.us[0] = f2bf(v1.x); pb.us[1] = f2bf(v1.y); pb.us[2] = f2bf(v1.z); pb.us[3] = f2bf(v1.w);
    uint2* dst = reinterpret_cast<uint2*>(xb + (size_t)row * K_DIM);
    dst[lane]      = pa.u2;
    dst[lane + 64] = pb.u2;
    #pragma unroll
    for (int off = 32; off; off >>= 1) ss += __shfl_xor(ss, off);
    if (lane == 0) x2[row] = ss * (1.0f / (float)K_DIM);
}

// ---- prep_cb: transpose cb [K=512][N=2048] f32 -> cbT [N][K] bf16, scaled by 2/D = 2^-8 ----
__global__ __launch_bounds__(256) void prep_cb_kernel(const float* __restrict__ cb,
                                                      unsigned short* __restrict__ cbT) {
    __shared__ float tile[32][65];
    const int k0 = blockIdx.x * 32;
    const int n0 = blockIdx.y * 64;
    const int tx = threadIdx.x & 63;
    const int ty = threadIdx.x >> 6;
    #pragma unroll
    for (int i = 0; i < 8; ++i) {
        const int k = ty + i * 4;
        tile[k][tx] = cb[(size_t)(k0 + k) * N_COLS + n0 + tx];
    }
    __syncthreads();
    const int kc = threadIdx.x & 31;
    const int nr = threadIdx.x >> 5;
    #pragma unroll
    for (int i = 0; i < 8; ++i) {
        const int n = nr + i * 8;
        cbT[(size_t)(n0 + n) * K_DIM + k0 + kc] = f2bf(tile[kc][n] * 0.00390625f);
    }
}

// ---- c2[n] = mean_k cb[k][n]^2 ----
__global__ __launch_bounds__(256) void c2_kernel(const float* __restrict__ cb,
                                                 float* __restrict__ c2) {
    __shared__ float p[4][64];
    const int t = threadIdx.x;
    const int nl = t & 63;
    const int kc = t >> 6;
    const int n = blockIdx.x * 64 + nl;
    float s = 0.0f;
    for (int k = kc * 128; k < kc * 128 + 128; ++k) {
        float v = cb[(size_t)k * N_COLS + n];
        s += v * v;
    }
    p[kc][nl] = s;
    __syncthreads();
    if (t < 64) {
        c2[blockIdx.x * 64 + t] =
            (p[0][t] + p[1][t] + p[2][t] + p[3][t]) * (1.0f / (float)K_DIM);
    }
}

// ======================= 128x128 GEMM, 256 thr, 3-deep =======================
// LDS per buf (shorts): A[128x32] @0 (4096), B[128x32] @4096 (4096) = 16KB; x3=48KB.

__device__ __forceinline__ bf16x8 frag_ld(const unsigned short* h, int r, int lhi) {
    const int off = r * 32 + ((lhi ^ ((r >> 1) & 3)) << 3);
    return *reinterpret_cast<const bf16x8*>(&h[off]);
}

#define BAR()  do { asm volatile("" ::: "memory"); \
                    __builtin_amdgcn_s_barrier();  \
                    asm volatile("" ::: "memory"); } while (0)
#define GATE_(n) asm volatile("s_waitcnt vmcnt(" #n ")" ::: "memory")
#define GATE(n) GATE_(n)

__global__ __launch_bounds__(256, 2) void gemm_kernel(
        const unsigned short* __restrict__ A,   // [M][K] bf16 (xb)
        const unsigned short* __restrict__ Bt,  // [N][K] bf16 (scaled by 2^-8)
        const float* __restrict__ x2,
        const float* __restrict__ c2,
        float* __restrict__ out) {
    __shared__ unsigned short smem[3][8192];    // 48 KiB

    const int tid  = threadIdx.x;
    const int wid  = tid >> 6;
    const int lane = tid & 63;
    const int wr64 = (wid >> 1) * 64;       // 2 M-waves
    const int wc64 = (wid & 1) * 64;        // 2 N-waves
    const int l15 = lane & 15;
    const int lhi = lane >> 4;

    // T1: XCD-bijective swizzle (4096 blocks -> 512/XCD); panel-major: the 16
    // n-blocks of one m-panel run consecutively on one XCD -> A panel (128KB)
    // + cbT (2MB) L2-resident.
    const int bid  = blockIdx.x;
    const int lbid = (bid & 7) * 512 + (bid >> 3);
    const int m0 = (lbid >> 4) * 128;
    const int n0 = (lbid & 15) * 128;

    const unsigned short* Ab = A  + (size_t)m0 * K_DIM;
    const unsigned short* Bb = Bt + (size_t)n0 * K_DIM;

    // staging geometry: 512 16B-chunks per tile; thread covers chunk tid and
    // 256+tid. chunk c -> row=c>>2, swizzled slot (c&3)^((row>>1)&3).
    const int c0   = tid;
    const int row0 = c0 >> 2;
    const size_t off0 = (size_t)row0 * K_DIM + ((size_t)(((c0 & 3) ^ ((row0 >> 1) & 3)) * 8));
    const int c1   = 256 + tid;
    const int row1 = c1 >> 2;
    const size_t off1 = (size_t)row1 * K_DIM + ((size_t)(((c1 & 3) ^ ((row1 >> 1) & 3)) * 8));

    f32x4 acc[4][4] = {};

#define STAGE(KT, BUF) do {                                                    \
    gload_lds16(Ab + off0 + (KT) * 32, &smem[(BUF)][wid * 512]);               \
    gload_lds16(Ab + off1 + (KT) * 32, &smem[(BUF)][2048 + wid * 512]);        \
    gload_lds16(Bb + off0 + (KT) * 32, &smem[(BUF)][4096 + wid * 512]);        \
    gload_lds16(Bb + off1 + (KT) * 32, &smem[(BUF)][6144 + wid * 512]); } while (0)

    // prologue: tiles 0,1 (4 ops each); GATE(4) -> tile0 landed, tile1 in flight
    STAGE(0, 0);
    STAGE(1, 1);
    GATE(4);
    BAR();

    #pragma unroll
    for (int t = 0; t < 16; ++t) {
        if (t < 14) STAGE(t + 2, (t + 2) % 3);
        const unsigned short* cbuf = smem[t % 3];
        bf16x8 b[4];
        #pragma unroll
        for (int nf = 0; nf < 4; ++nf)
            b[nf] = frag_ld(cbuf + 4096, wc64 + nf * 16 + l15, lhi);
        __builtin_amdgcn_s_setprio(1);
        #pragma unroll
        for (int mf = 0; mf < 4; ++mf) {
            const bf16x8 a = frag_ld(cbuf, wr64 + mf * 16 + l15, lhi);
            #pragma unroll
            for (int nf = 0; nf < 4; ++nf)
                acc[mf][nf] = __builtin_amdgcn_mfma_f32_16x16x32_bf16(a, b[nf], acc[mf][nf], 0, 0, 0);
        }
        __builtin_amdgcn_s_setprio(0);
        // gate: tile t+1 landed (t+2's 4 ops stay in flight; never drain mid-loop)
        if (t < 14) { GATE(4); } else if (t == 14) { GATE(0); }
        BAR();
    }
#undef STAGE

    // epilogue: C/D layout col = lane&15, row = (lane>>4)*4 + reg
    #pragma unroll
    for (int mf = 0; mf < 4; ++mf) {
        const int mrow = m0 + wr64 + mf * 16 + lhi * 4;
        const float xv0 = x2[mrow + 0];
        const float xv1 = x2[mrow + 1];
        const float xv2 = x2[mrow + 2];
        const float xv3 = x2[mrow + 3];
        #pragma unroll
        for (int nf = 0; nf < 4; ++nf) {
            const int col = n0 + wc64 + nf * 16 + l15;
            const float cv = c2[col];
            float* o = out + (size_t)mrow * N_COLS + col;
            o[0 * N_COLS] = xv0 + cv - acc[mf][nf][0];
            o[1 * N_COLS] = xv1 + cv - acc[mf][nf][1];
            o[2 * N_COLS] = xv2 + cv - acc[mf][nf][2];
            o[3 * N_COLS] = xv3 + cv - acc[mf][nf][3];
        }
    }
}

extern "C" void kernel_launch(void* const* d_in, const int* in_sizes, int n_in,
                              void* d_out, int out_size, void* d_ws, size_t ws_size,
                              hipStream_t stream) {
    const float* x  = (const float*)d_in[0];   // [8,4096,512]
    const float* cb = (const float*)d_in[1];   // [1,1,512,2048]
    float* out = (float*)d_out;                // [8,4096,2048]

    char* ws = (char*)d_ws;
    unsigned short* xb  = (unsigned short*)ws;                               // 32 MB
    unsigned short* cbT = (unsigned short*)(ws + (size_t)33554432);          // 2 MB
    float* x2 = (float*)(ws + (size_t)33554432 + 2097152);                   // 128 KB
    float* c2 = (float*)(ws + (size_t)33554432 + 2097152 + 131072);          // 8 KB

    prep_x_kernel<<<M_ROWS / 4, 256, 0, stream>>>(x, xb, x2);
    prep_cb_kernel<<<dim3(16, 32), 256, 0, stream>>>(cb, cbT);
    c2_kernel<<<N_COLS / 64, 256, 0, stream>>>(cb, c2);
    gemm_kernel<<<dim3((M_ROWS / 128) * (N_COLS / 128)), 256, 0, stream>>>(xb, cbT, x2, c2, out);
}